// Round 2
// baseline (355.904 us; speedup 1.0000x reference)
//
#include <hip/hip_runtime.h>
#include <math.h>

#define N_NODES 12288
#define N_EDGES 393216
#define DIM 64
#define EPS 1e-8f

__device__ __forceinline__ float wave_sum(float v) {
    // full 64-lane butterfly reduction; all lanes end with the total
    #pragma unroll
    for (int off = 32; off; off >>= 1) v += __shfl_xor(v, off);
    return v;
}

// Phase 1: per node i compute
//   y_self = x_i @ W_self^T, y_neigh = x_i @ W_neigh^T
//   s_norm[i]  = y_self / (||y_self|| + eps)     (self_trans feat)
//   anf[i]     = y_neigh / (||y_neigh|| + eps)   (all_nodes feat)
//   accum[i]   = anf[i]      (diagonal A[i,i]=1.0 contribution from eye)
//   Ssum[i]    = 1.0
//   xnorm[i]   = ||x_i||
// Layout: 256 threads = 4 waves; wave per row; lane = output dim o.
__global__ __launch_bounds__(256) void phase1_kernel(
    const float* __restrict__ x, const float* __restrict__ Wself,
    const float* __restrict__ Wneigh,
    float* __restrict__ s_norm, float* __restrict__ anf,
    float* __restrict__ accum, float* __restrict__ Ssum,
    float* __restrict__ xnorm) {
    __shared__ float Wl[2 * 64 * 65];   // +1 pad: lane o reads row o -> 2-way bank (free, m136)
    const int tid = threadIdx.x;
    for (int idx = tid; idx < 4096; idx += 256) {
        int o = idx >> 6, k = idx & 63;
        Wl[o * 65 + k]            = Wself[idx];
        Wl[64 * 65 + o * 65 + k]  = Wneigh[idx];
    }
    __syncthreads();

    const int o = tid & 63;
    const int i = blockIdx.x * 4 + (tid >> 6);
    const float xo = x[(size_t)i * 64 + o];

    float ys = 0.f, yn = 0.f;
    #pragma unroll
    for (int k = 0; k < 64; ++k) {
        float xk = __shfl(xo, k);
        ys = fmaf(xk, Wl[o * 65 + k], ys);
        yn = fmaf(xk, Wl[64 * 65 + o * 65 + k], yn);
    }

    float nys = sqrtf(wave_sum(ys * ys));
    float nyn = sqrtf(wave_sum(yn * yn));
    float nx  = sqrtf(wave_sum(xo * xo));

    float sd = ys / (nys + EPS);
    float ad = yn / (nyn + EPS);
    s_norm[(size_t)i * 64 + o] = sd;
    anf[(size_t)i * 64 + o]    = ad;
    accum[(size_t)i * 64 + o]  = ad;   // eye: A[i,i] = 1.0 * anf[i]
    if (o == 0) { Ssum[i] = 1.0f; xnorm[i] = nx; }
}

// Phase 2: one wave per DIRECTED pair p in [0, 2E).
// Dedup via N^2 bitmap (set-semantics of the reference's .at[].set():
// duplicate directed pairs contribute w exactly ONCE, not summed).
// Owner wave computes w and atomically accumulates w * anf[b] into row a.
// Self-loop (a==b): reference's .set(w) overwrites the eye's 1.0 -> add (w-1).
// Loads are issued SPECULATIVELY before the dedup result is known: dup rate
// ~0.1%, and this breaks the atomicOr->load serial dependency chain.
__global__ __launch_bounds__(256) void edge_kernel(
    const float* __restrict__ x, const int* __restrict__ ei,
    const float* __restrict__ xnorm, const float* __restrict__ anf,
    float* __restrict__ accum, float* __restrict__ Ssum,
    unsigned int* __restrict__ bitmap) {
    const int lane = threadIdx.x & 63;
    const int wave = blockIdx.x * 4 + (threadIdx.x >> 6);
    const int nwaves = gridDim.x * 4;
    const int P = 2 * N_EDGES;

    for (int p = wave; p < P; p += nwaves) {
        const int e = p >> 1;
        const int r = ei[e];
        const int c = ei[N_EDGES + e];
        const int a = (p & 1) ? c : r;
        const int b = (p & 1) ? r : c;

        // ---- speculative loads (independent of dedup outcome) ----
        const float xa  = x[(size_t)a * 64 + lane];
        const float xb  = x[(size_t)b * 64 + lane];
        const float ab  = anf[(size_t)b * 64 + lane];
        const float nxa = xnorm[a];
        const float nxb = xnorm[b];

        // ---- dedup (ownership of ordered pair (a,b)) ----
        int owned = 0;
        if (lane == 0) {
            unsigned idx = (unsigned)a * (unsigned)N_NODES + (unsigned)b;
            unsigned old = atomicOr(&bitmap[idx >> 5], 1u << (idx & 31));
            owned = (int)(((old >> (idx & 31)) & 1u) ^ 1u);
        }
        owned = __shfl(owned, 0);
        if (!owned) continue;

        const float dot  = wave_sum(xa * xb);
        const float cosv = dot / (nxa * nxb + EPS);
        float w = (cosv + 1.0f) * 0.5f;
        w = fminf(fmaxf(w, 0.1f), 0.9f);
        const float scale = (a == b) ? (w - 1.0f) : w;

        atomicAdd(&accum[(size_t)a * 64 + lane], scale * ab);
        if (lane == 0) atomicAdd(&Ssum[a], scale);
    }
}

// Phase 3: per node, finish the projective chain. Wave per node, lane = dim.
__global__ __launch_bounds__(256) void finalize_kernel(
    const float* __restrict__ s_norm, const float* __restrict__ accum,
    const float* __restrict__ Ssum, const float* __restrict__ bias,
    float* __restrict__ out) {
    const int lane = threadIdx.x & 63;
    const int i = blockIdx.x * 4 + (threadIdx.x >> 6);

    const float S = Ssum[i];
    const float u = accum[(size_t)i * 64 + lane];
    const float v = u / (S + EPS);                 // (adj/rowsum) @ all_nodes, feat part
    const float nv = sqrtf(wave_sum(v * v));
    const float nf = v / (nv + EPS);               // neigh_trans feat

    const float s = s_norm[(size_t)i * 64 + lane]; // self_trans feat
    const float h = 0.5f * (s + nf);               // first average, feat part
    const float nh = sqrtf(wave_sum(h * h));
    const float hf = h / (nh + EPS);

    const float bd = bias[lane];
    const float nb = sqrtf(wave_sum(bd * bd) + 1.0f);  // ||[bias,1]||, no eps
    const float g = 0.9f * hf + 0.1f * (bd / nb);      // second average, feat part
    const float ng = sqrtf(wave_sum(g * g));
    const float gf = g / (ng + EPS);

    const float rho = ng / (ng + EPS);             // == ||gf||
    out[(size_t)i * 64 + lane] = gf / (rho + EPS);
}

extern "C" void kernel_launch(void* const* d_in, const int* in_sizes, int n_in,
                              void* d_out, int out_size, void* d_ws, size_t ws_size,
                              hipStream_t stream) {
    const float* x      = (const float*)d_in[0];
    const int*   ei     = (const int*)  d_in[1];
    const float* Wself  = (const float*)d_in[2];
    const float* Wneigh = (const float*)d_in[3];
    const float* bias   = (const float*)d_in[4];
    float* out = (float*)d_out;

    // workspace carve-up (total ~28.4 MB)
    const size_t BITMAP_BYTES = ((size_t)N_NODES * N_NODES) / 8;       // 18,874,368
    const size_t ROW_BYTES    = (size_t)N_NODES * 64 * sizeof(float);  // 3,145,728
    char* ws = (char*)d_ws;
    unsigned int* bitmap = (unsigned int*)ws;             ws += BITMAP_BYTES;
    float* accum  = (float*)ws;                           ws += ROW_BYTES;
    float* s_norm = (float*)ws;                           ws += ROW_BYTES;
    float* anf    = (float*)ws;                           ws += ROW_BYTES;
    float* Ssum   = (float*)ws;                           ws += (size_t)N_NODES * sizeof(float);
    float* xnorm  = (float*)ws;

    hipMemsetAsync(bitmap, 0, BITMAP_BYTES, stream);

    phase1_kernel<<<N_NODES / 4, 256, 0, stream>>>(x, Wself, Wneigh,
                                                   s_norm, anf, accum, Ssum, xnorm);

    edge_kernel<<<8192, 256, 0, stream>>>(x, ei, xnorm, anf, accum, Ssum, bitmap);

    finalize_kernel<<<N_NODES / 4, 256, 0, stream>>>(s_norm, accum, Ssum, bias, out);
}

// Round 3
// 300.286 us; speedup vs baseline: 1.1852x; 1.1852x over previous
//
#include <hip/hip_runtime.h>
#include <math.h>

#define N_NODES 12288
#define N_EDGES 393216
#define DIM 64
#define EPS 1e-8f
#define SLOTS 192   // per-node neighbor-list capacity; mean deg=64, P(>192)~1e-15

__device__ __forceinline__ float wave_sum(float v) {
    #pragma unroll
    for (int off = 32; off; off >>= 1) v += __shfl_xor(v, off);
    return v;
}

// Phase 1: per node i: y_self = x_i@Wself^T, y_neigh = x_i@Wneigh^T,
// s_norm = y_self/(||y_self||+eps), anf = y_neigh/(||y_neigh||+eps), xnorm = ||x_i||.
// 4 waves/block, wave per node, lane = output dim.
__global__ __launch_bounds__(256) void phase1_kernel(
    const float* __restrict__ x, const float* __restrict__ Wself,
    const float* __restrict__ Wneigh,
    float* __restrict__ s_norm, float* __restrict__ anf,
    float* __restrict__ xnorm) {
    __shared__ float Wl[2 * 64 * 65];   // +1 pad: 2-way bank alias is free (m136)
    const int tid = threadIdx.x;
    for (int idx = tid; idx < 4096; idx += 256) {
        int o = idx >> 6, k = idx & 63;
        Wl[o * 65 + k]           = Wself[idx];
        Wl[64 * 65 + o * 65 + k] = Wneigh[idx];
    }
    __syncthreads();

    const int o = tid & 63;
    const int i = blockIdx.x * 4 + (tid >> 6);
    const float xo = x[(size_t)i * 64 + o];

    float ys = 0.f, yn = 0.f;
    #pragma unroll
    for (int k = 0; k < 64; ++k) {
        float xk = __shfl(xo, k);
        ys = fmaf(xk, Wl[o * 65 + k], ys);
        yn = fmaf(xk, Wl[64 * 65 + o * 65 + k], yn);
    }

    float nys = sqrtf(wave_sum(ys * ys));
    float nyn = sqrtf(wave_sum(yn * yn));
    float nx  = sqrtf(wave_sum(xo * xo));

    s_norm[(size_t)i * 64 + o] = ys / (nys + EPS);
    anf[(size_t)i * 64 + o]    = yn / (nyn + EPS);
    if (o == 0) xnorm[i] = nx;
}

// Phase 2: one wave per UNDIRECTED edge e. Compute w once (symmetric), then
// append (c,w') to r's bucket and (r,w') to c's bucket via a 4B cursor atomic.
// NO dedup here (exact dedup happens in-register during the gather).
// Self-edge (r==c): reference's .set(w) overwrites eye's 1.0 -> store w-1
// so the gather (which starts from the 1.0*anf diag) lands on w exactly.
__global__ __launch_bounds__(256) void edge_scatter_kernel(
    const float* __restrict__ x, const int* __restrict__ ei,
    const float* __restrict__ xnorm,
    int* __restrict__ deg, int2* __restrict__ meta) {
    const int lane = threadIdx.x & 63;
    const int e = blockIdx.x * 4 + (threadIdx.x >> 6);
    if (e >= N_EDGES) return;

    const int r = ei[e];
    const int c = ei[N_EDGES + e];

    const float xa = x[(size_t)r * 64 + lane];
    const float xb = x[(size_t)c * 64 + lane];
    const float dot = wave_sum(xa * xb);
    const float cosv = dot / (xnorm[r] * xnorm[c] + EPS);
    float w = (cosv + 1.0f) * 0.5f;
    w = fminf(fmaxf(w, 0.1f), 0.9f);
    const float wv = (r == c) ? (w - 1.0f) : w;
    const int wbits = __float_as_int(wv);

    if (lane == 0) {
        int s = atomicAdd(&deg[r], 1);
        if (s < SLOTS) meta[(size_t)r * SLOTS + s] = make_int2(c, wbits);
    } else if (lane == 1) {
        int s = atomicAdd(&deg[c], 1);
        if (s < SLOTS) meta[(size_t)c * SLOTS + s] = make_int2(r, wbits);
    }
}

// Phase 3: wave per node. Read the node's neighbor list in 64-entry chunks,
// mark duplicates (entry equal to any EARLIER entry -> exact .set semantics;
// all instances of (a,b) carry identical w, so keeping the first is exact),
// accumulate acc = anf[a] + sum w*anf[b], S = 1 + sum w, then run the full
// projective chain to out.
__global__ __launch_bounds__(256) void gather_finalize_kernel(
    const int* __restrict__ deg, const int2* __restrict__ meta,
    const float* __restrict__ anf, const float* __restrict__ s_norm,
    const float* __restrict__ bias, float* __restrict__ out) {
    const int lane = threadIdx.x & 63;
    const int i = blockIdx.x * 4 + (threadIdx.x >> 6);

    const int d = min(deg[i], SLOTS);
    float acc = anf[(size_t)i * 64 + lane];   // eye diagonal: 1.0 * anf[i]
    float S = 1.0f;

    for (int base = 0; base < d; base += 64) {
        const int m = min(64, d - base);
        int2 mt = (lane < m) ? meta[(size_t)i * SLOTS + base + lane]
                             : make_int2(-1, 0);
        const int   cl = mt.x;
        const float wl = __int_as_float(mt.y);

        // intra-chunk: dup if an earlier lane in this chunk has the same col
        int dup = 0;
        #pragma unroll
        for (int s = 1; s < 64; ++s) {
            int v = __shfl_up(cl, s);
            dup |= (lane >= s && v == cl);
        }
        // cross-chunk: dup if any entry of a previous (full) chunk matches
        for (int pb = 0; pb < base; pb += 64) {
            int pc = meta[(size_t)i * SLOTS + pb + lane].x;
            #pragma unroll
            for (int k = 0; k < 64; ++k) {
                dup |= (__shfl(pc, k) == cl);
            }
        }

        // gather this chunk (dup flag & index are wave-uniform per k)
        #pragma unroll 4
        for (int k = 0; k < m; ++k) {
            const int b   = __shfl(cl, k);
            const int dk  = __shfl(dup, k);
            const float wv = __shfl(wl, k);
            if (!dk) {
                acc = fmaf(wv, anf[(size_t)b * 64 + lane], acc);
                S += wv;
            }
        }
    }

    // ---- projective chain (verified passing in R2) ----
    const float v = acc / (S + EPS);               // row-normalized neigh agg
    const float nv = sqrtf(wave_sum(v * v));
    const float nf = v / (nv + EPS);               // neigh_trans feat

    const float s = s_norm[(size_t)i * 64 + lane]; // self_trans feat
    const float h = 0.5f * (s + nf);
    const float nh = sqrtf(wave_sum(h * h));
    const float hf = h / (nh + EPS);

    const float bd = bias[lane];
    const float nb = sqrtf(wave_sum(bd * bd) + 1.0f);   // ||[bias,1]||, no eps
    const float g = 0.9f * hf + 0.1f * (bd / nb);
    const float ng = sqrtf(wave_sum(g * g));
    const float gf = g / (ng + EPS);

    const float rho = ng / (ng + EPS);
    out[(size_t)i * 64 + lane] = gf / (rho + EPS);
}

extern "C" void kernel_launch(void* const* d_in, const int* in_sizes, int n_in,
                              void* d_out, int out_size, void* d_ws, size_t ws_size,
                              hipStream_t stream) {
    const float* x      = (const float*)d_in[0];
    const int*   ei     = (const int*)  d_in[1];
    const float* Wself  = (const float*)d_in[2];
    const float* Wneigh = (const float*)d_in[3];
    const float* bias   = (const float*)d_in[4];
    float* out = (float*)d_out;

    // workspace carve-up (~25.1 MB)
    const size_t ROW_BYTES = (size_t)N_NODES * 64 * sizeof(float);  // 3,145,728
    char* ws = (char*)d_ws;
    int*  deg    = (int*)ws;      ws += (size_t)N_NODES * sizeof(int);       // 48 KB
    int2* meta   = (int2*)ws;     ws += (size_t)N_NODES * SLOTS * sizeof(int2); // 18.87 MB
    float* s_norm = (float*)ws;   ws += ROW_BYTES;
    float* anf    = (float*)ws;   ws += ROW_BYTES;
    float* xnorm  = (float*)ws;

    hipMemsetAsync(deg, 0, (size_t)N_NODES * sizeof(int), stream);

    phase1_kernel<<<N_NODES / 4, 256, 0, stream>>>(x, Wself, Wneigh,
                                                   s_norm, anf, xnorm);

    edge_scatter_kernel<<<(N_EDGES + 3) / 4, 256, 0, stream>>>(x, ei, xnorm,
                                                               deg, meta);

    gather_finalize_kernel<<<N_NODES / 4, 256, 0, stream>>>(deg, meta, anf,
                                                            s_norm, bias, out);
}

// Round 4
// 165.146 us; speedup vs baseline: 2.1551x; 1.8183x over previous
//
#include <hip/hip_runtime.h>
#include <math.h>

#define N_NODES 12288
#define N_EDGES 393216
#define DIM 64
#define EPS 1e-8f
#define SLOTS 192   // per-node list capacity; deg~Poisson(64), P(>192) ~ 1e-30

__device__ __forceinline__ float wave_sum(float v) {
    #pragma unroll
    for (int off = 32; off; off >>= 1) v += __shfl_xor(v, off);
    return v;
}

// Phase 1 (unchanged from R3 - passing, not the bottleneck): per node i:
//   s_norm = (x_i@Wself^T)/(||.||+eps), anf = (x_i@Wneigh^T)/(||.||+eps), xnorm=||x_i||
__global__ __launch_bounds__(256) void phase1_kernel(
    const float* __restrict__ x, const float* __restrict__ Wself,
    const float* __restrict__ Wneigh,
    float* __restrict__ s_norm, float* __restrict__ anf,
    float* __restrict__ xnorm) {
    __shared__ float Wl[2 * 64 * 65];   // +1 pad: 2-way bank alias is free (m136)
    const int tid = threadIdx.x;
    for (int idx = tid; idx < 4096; idx += 256) {
        int o = idx >> 6, k = idx & 63;
        Wl[o * 65 + k]           = Wself[idx];
        Wl[64 * 65 + o * 65 + k] = Wneigh[idx];
    }
    __syncthreads();

    const int o = tid & 63;
    const int i = blockIdx.x * 4 + (tid >> 6);
    const float xo = x[(size_t)i * 64 + o];

    float ys = 0.f, yn = 0.f;
    #pragma unroll
    for (int k = 0; k < 64; ++k) {
        float xk = __shfl(xo, k);
        ys = fmaf(xk, Wl[o * 65 + k], ys);
        yn = fmaf(xk, Wl[64 * 65 + o * 65 + k], yn);
    }

    float nys = sqrtf(wave_sum(ys * ys));
    float nyn = sqrtf(wave_sum(yn * yn));
    float nx  = sqrtf(wave_sum(xo * xo));

    s_norm[(size_t)i * 64 + o] = ys / (nys + EPS);
    anf[(size_t)i * 64 + o]    = yn / (nyn + EPS);
    if (o == 0) xnorm[i] = nx;
}

// Phase 2: 8 lanes per edge, 8 edges per wave (49152 waves vs 393216 before).
// Each 8-lane group computes the 64-dim dot via 8 elems/lane + 3x shfl_xor,
// then lanes j=0/j=1 append (c,w') / (r,w') to the two buckets in parallel.
// Self-edge r==c: reference's .set(w) overwrites the eye's 1.0+1.0-set chain
// ending at w -> store w-1 (both appended copies identical; gather dedups).
__global__ __launch_bounds__(256) void edge_scatter_kernel(
    const float* __restrict__ x, const int* __restrict__ ei,
    const float* __restrict__ xnorm,
    int* __restrict__ deg, int2* __restrict__ meta) {
    const int lane = threadIdx.x & 63;
    const int j = lane & 7;                       // position within edge group
    const int wave = blockIdx.x * 4 + (threadIdx.x >> 6);
    const int e = wave * 8 + (lane >> 3);         // N_EDGES = 8*49152 exactly

    const int r = ei[e];
    const int c = ei[N_EDGES + e];

    const size_t rb = (size_t)r * 64 + j * 8;
    const size_t cb = (size_t)c * 64 + j * 8;
    const float4 xr0 = *(const float4*)&x[rb];
    const float4 xr1 = *(const float4*)&x[rb + 4];
    const float4 xc0 = *(const float4*)&x[cb];
    const float4 xc1 = *(const float4*)&x[cb + 4];

    float p = xr0.x*xc0.x + xr0.y*xc0.y + xr0.z*xc0.z + xr0.w*xc0.w
            + xr1.x*xc1.x + xr1.y*xc1.y + xr1.z*xc1.z + xr1.w*xc1.w;
    p += __shfl_xor(p, 1);
    p += __shfl_xor(p, 2);
    p += __shfl_xor(p, 4);                        // all 8 lanes of group hold dot

    const float cosv = p / (xnorm[r] * xnorm[c] + EPS);
    float w = fminf(fmaxf((cosv + 1.0f) * 0.5f, 0.1f), 0.9f);
    const float wv = (r == c) ? (w - 1.0f) : w;
    const int wbits = __float_as_int(wv);

    if (j == 0) {
        int s = atomicAdd(&deg[r], 1);
        if (s < SLOTS) meta[(size_t)r * SLOTS + s] = make_int2(c, wbits);
    } else if (j == 1) {
        int s = atomicAdd(&deg[c], 1);
        if (s < SLOTS) meta[(size_t)c * SLOTS + s] = make_int2(r, wbits);
    }
}

// Phase 3: wave per node. Stage the full neighbor list in LDS (coalesced),
// dedup via wave-uniform broadcast ds_reads (exact .set semantics: duplicate
// (a,b) entries carry identical w; keep first, zero the rest's w in LDS),
// then branch-free gather: acc += w_k * anf[b_k]. Zero shuffles in the hot
// path -> SQ_LDS_BANK_CONFLICT (bpermute) should collapse.
__global__ __launch_bounds__(256) void gather_finalize_kernel(
    const int* __restrict__ deg, const int2* __restrict__ meta,
    const float* __restrict__ anf, const float* __restrict__ s_norm,
    const float* __restrict__ bias, float* __restrict__ out) {
    __shared__ int2 cw[4][SLOTS];                 // 6 KB/block
    const int lane = threadIdx.x & 63;
    const int w4 = threadIdx.x >> 6;
    const int i = blockIdx.x * 4 + w4;

    const int d = min(deg[i], SLOTS);

    // ---- stage list to LDS, keeping own entries in registers (<=3) ----
    int2 m0 = make_int2(-1, 0), m1 = make_int2(-1, 0), m2 = make_int2(-1, 0);
    if (lane < d)       { m0 = meta[(size_t)i * SLOTS + lane];       cw[w4][lane]       = m0; }
    if (lane + 64 < d)  { m1 = meta[(size_t)i * SLOTS + lane + 64];  cw[w4][lane + 64]  = m1; }
    if (lane + 128 < d) { m2 = meta[(size_t)i * SLOTS + lane + 128]; cw[w4][lane + 128] = m2; }
    __syncthreads();

    // ---- dedup: entry at slot g is dup iff an earlier slot has same col ----
    int dup0 = 0, dup1 = 0, dup2 = 0;
    for (int s = 0; s < d; ++s) {
        const int cs = cw[w4][s].x;               // uniform addr -> broadcast
        dup0 |= (s < lane)       & (cs == m0.x);
        dup1 |= (s < lane + 64)  & (cs == m1.x);
        dup2 |= (s < lane + 128) & (cs == m2.x);
    }

    // ---- zero dup weights in LDS; accumulate row-sum of kept weights ----
    float Sp = 0.f;
    if (lane < d)       { if (dup0) cw[w4][lane].y       = 0; else Sp += __int_as_float(m0.y); }
    if (lane + 64 < d)  { if (dup1) cw[w4][lane + 64].y  = 0; else Sp += __int_as_float(m1.y); }
    if (lane + 128 < d) { if (dup2) cw[w4][lane + 128].y = 0; else Sp += __int_as_float(m2.y); }
    const float S = 1.0f + wave_sum(Sp);          // 1.0 = eye diagonal
    __syncthreads();

    // ---- branch-free gather: dups contribute w=0 ----
    float acc = anf[(size_t)i * 64 + lane];       // diagonal: 1.0 * anf[i]
    #pragma unroll 8
    for (int k = 0; k < d; ++k) {
        const int2 ent = cw[w4][k];               // broadcast ds_read_b64
        acc = fmaf(__int_as_float(ent.y), anf[(size_t)ent.x * 64 + lane], acc);
    }

    // ---- projective chain (verified in R2/R3) ----
    const float v = acc / (S + EPS);
    const float nv = sqrtf(wave_sum(v * v));
    const float nf = v / (nv + EPS);              // neigh_trans feat

    const float s = s_norm[(size_t)i * 64 + lane];
    const float h = 0.5f * (s + nf);
    const float nh = sqrtf(wave_sum(h * h));
    const float hf = h / (nh + EPS);

    const float bd = bias[lane];
    const float nb = sqrtf(wave_sum(bd * bd) + 1.0f);  // ||[bias,1]||, no eps
    const float g = 0.9f * hf + 0.1f * (bd / nb);
    const float ng = sqrtf(wave_sum(g * g));
    const float gf = g / (ng + EPS);

    const float rho = ng / (ng + EPS);
    out[(size_t)i * 64 + lane] = gf / (rho + EPS);
}

extern "C" void kernel_launch(void* const* d_in, const int* in_sizes, int n_in,
                              void* d_out, int out_size, void* d_ws, size_t ws_size,
                              hipStream_t stream) {
    const float* x      = (const float*)d_in[0];
    const int*   ei     = (const int*)  d_in[1];
    const float* Wself  = (const float*)d_in[2];
    const float* Wneigh = (const float*)d_in[3];
    const float* bias   = (const float*)d_in[4];
    float* out = (float*)d_out;

    // workspace carve-up (~25.1 MB)
    const size_t ROW_BYTES = (size_t)N_NODES * 64 * sizeof(float);
    char* ws = (char*)d_ws;
    int*  deg    = (int*)ws;      ws += (size_t)N_NODES * sizeof(int);
    int2* meta   = (int2*)ws;     ws += (size_t)N_NODES * SLOTS * sizeof(int2);
    float* s_norm = (float*)ws;   ws += ROW_BYTES;
    float* anf    = (float*)ws;   ws += ROW_BYTES;
    float* xnorm  = (float*)ws;

    hipMemsetAsync(deg, 0, (size_t)N_NODES * sizeof(int), stream);

    phase1_kernel<<<N_NODES / 4, 256, 0, stream>>>(x, Wself, Wneigh,
                                                   s_norm, anf, xnorm);

    edge_scatter_kernel<<<N_EDGES / 8 / 4, 256, 0, stream>>>(x, ei, xnorm,
                                                             deg, meta);

    gather_finalize_kernel<<<N_NODES / 4, 256, 0, stream>>>(deg, meta, anf,
                                                            s_norm, bias, out);
}

// Round 5
// 157.661 us; speedup vs baseline: 2.2574x; 1.0475x over previous
//
#include <hip/hip_runtime.h>
#include <math.h>

#define N_NODES 12288
#define N_EDGES 393216
#define DIM 64
#define EPS 1e-8f
#define SLOTS 192   // per-node list capacity; deg~Poisson(64), P(>192) ~ 1e-30

__device__ __forceinline__ float wave_sum(float v) {
    #pragma unroll
    for (int off = 32; off; off >>= 1) v += __shfl_xor(v, off);
    return v;
}

// Phase 1: per node i: s_norm = (x_i@Wself^T)/(||.||+eps),
//                      anf    = (x_i@Wneigh^T)/(||.||+eps)
// v2: x-row read via wave-uniform float4 global loads (L1 broadcast) -- zero
// bpermutes in the hot loop. W in 65-padded LDS: lane o reads row o, bank
// (o*65+k)%32 = (o+k)%32 -> 2-way alias only (free, m136); adjacent k pairs
// merge to ds_read2_b32.
__global__ __launch_bounds__(256) void phase1_kernel(
    const float* __restrict__ x, const float* __restrict__ Wself,
    const float* __restrict__ Wneigh,
    float* __restrict__ s_norm, float* __restrict__ anf) {
    __shared__ float Wl[2 * 64 * 65];   // 33.3 KB
    const int tid = threadIdx.x;

    // vectorized staging: 1024 float4 per matrix, 256 threads -> 4 each
    #pragma unroll
    for (int v = 0; v < 4; ++v) {
        const int idx4 = v * 256 + tid;           // float4 index in [0,1024)
        const int o = idx4 >> 4, k4 = (idx4 & 15) << 2;
        const float4 a = *(const float4*)&Wself[idx4 << 2];
        Wl[o * 65 + k4 + 0] = a.x; Wl[o * 65 + k4 + 1] = a.y;
        Wl[o * 65 + k4 + 2] = a.z; Wl[o * 65 + k4 + 3] = a.w;
        const float4 b = *(const float4*)&Wneigh[idx4 << 2];
        float* W2 = &Wl[64 * 65];
        W2[o * 65 + k4 + 0] = b.x; W2[o * 65 + k4 + 1] = b.y;
        W2[o * 65 + k4 + 2] = b.z; W2[o * 65 + k4 + 3] = b.w;
    }
    __syncthreads();

    const int o = tid & 63;
    const int i = blockIdx.x * 4 + (tid >> 6);
    const float* xr = &x[(size_t)i * 64];

    float ys = 0.f, yn = 0.f;
    #pragma unroll
    for (int t = 0; t < 16; ++t) {
        const float4 xv = *(const float4*)&xr[4 * t];   // wave-uniform addr
        const int kb = 4 * t;
        ys = fmaf(xv.x, Wl[o * 65 + kb + 0], ys);
        ys = fmaf(xv.y, Wl[o * 65 + kb + 1], ys);
        ys = fmaf(xv.z, Wl[o * 65 + kb + 2], ys);
        ys = fmaf(xv.w, Wl[o * 65 + kb + 3], ys);
        yn = fmaf(xv.x, Wl[64 * 65 + o * 65 + kb + 0], yn);
        yn = fmaf(xv.y, Wl[64 * 65 + o * 65 + kb + 1], yn);
        yn = fmaf(xv.z, Wl[64 * 65 + o * 65 + kb + 2], yn);
        yn = fmaf(xv.w, Wl[64 * 65 + o * 65 + kb + 3], yn);
    }

    const float nys = sqrtf(wave_sum(ys * ys));
    const float nyn = sqrtf(wave_sum(yn * yn));
    s_norm[(size_t)i * 64 + o] = ys / (nys + EPS);
    anf[(size_t)i * 64 + o]    = yn / (nyn + EPS);
}

// Phase 2: 8 lanes per edge, 8 edges per wave. Norms computed INLINE from the
// already-loaded rows (no xnorm dependency -> scatter only needs memset(deg)).
// Self-edge r==c: reference's .set(w) overwrites the (1.0-set + eye) diagonal
// -> store w-1 (gather starts from the eye's 1.0*anf[i]; dedup keeps one copy).
__global__ __launch_bounds__(256) void edge_scatter_kernel(
    const float* __restrict__ x, const int* __restrict__ ei,
    int* __restrict__ deg, int2* __restrict__ meta) {
    const int lane = threadIdx.x & 63;
    const int j = lane & 7;                       // position within edge group
    const int wave = blockIdx.x * 4 + (threadIdx.x >> 6);
    const int e = wave * 8 + (lane >> 3);         // N_EDGES = 8*49152 exactly

    const int r = ei[e];
    const int c = ei[N_EDGES + e];

    const size_t rb = (size_t)r * 64 + j * 8;
    const size_t cb = (size_t)c * 64 + j * 8;
    const float4 xr0 = *(const float4*)&x[rb];
    const float4 xr1 = *(const float4*)&x[rb + 4];
    const float4 xc0 = *(const float4*)&x[cb];
    const float4 xc1 = *(const float4*)&x[cb + 4];

    float p = xr0.x*xc0.x + xr0.y*xc0.y + xr0.z*xc0.z + xr0.w*xc0.w
            + xr1.x*xc1.x + xr1.y*xc1.y + xr1.z*xc1.z + xr1.w*xc1.w;
    float nr = xr0.x*xr0.x + xr0.y*xr0.y + xr0.z*xr0.z + xr0.w*xr0.w
             + xr1.x*xr1.x + xr1.y*xr1.y + xr1.z*xr1.z + xr1.w*xr1.w;
    float nc = xc0.x*xc0.x + xc0.y*xc0.y + xc0.z*xc0.z + xc0.w*xc0.w
             + xc1.x*xc1.x + xc1.y*xc1.y + xc1.z*xc1.z + xc1.w*xc1.w;
    #pragma unroll
    for (int off = 1; off < 8; off <<= 1) {
        p  += __shfl_xor(p,  off);
        nr += __shfl_xor(nr, off);
        nc += __shfl_xor(nc, off);
    }

    const float cosv = p / (sqrtf(nr) * sqrtf(nc) + EPS);
    float w = fminf(fmaxf((cosv + 1.0f) * 0.5f, 0.1f), 0.9f);
    const float wv = (r == c) ? (w - 1.0f) : w;
    const int wbits = __float_as_int(wv);

    if (j == 0) {
        int s = atomicAdd(&deg[r], 1);
        if (s < SLOTS) meta[(size_t)r * SLOTS + s] = make_int2(c, wbits);
    } else if (j == 1) {
        int s = atomicAdd(&deg[c], 1);
        if (s < SLOTS) meta[(size_t)c * SLOTS + s] = make_int2(r, wbits);
    }
}

// Phase 3: wave per node. Stage list in LDS (coalesced), dedup via broadcast
// ds_reads (exact .set semantics: duplicate (a,b) entries carry identical w;
// keep first, zero the rest), branch-free gather, projective chain.
__global__ __launch_bounds__(256) void gather_finalize_kernel(
    const int* __restrict__ deg, const int2* __restrict__ meta,
    const float* __restrict__ anf, const float* __restrict__ s_norm,
    const float* __restrict__ bias, float* __restrict__ out) {
    __shared__ int2 cw[4][SLOTS];                 // 6 KB/block
    const int lane = threadIdx.x & 63;
    const int w4 = threadIdx.x >> 6;
    const int i = blockIdx.x * 4 + w4;

    const int d = min(deg[i], SLOTS);

    int2 m0 = make_int2(-1, 0), m1 = make_int2(-1, 0), m2 = make_int2(-1, 0);
    if (lane < d)       { m0 = meta[(size_t)i * SLOTS + lane];       cw[w4][lane]       = m0; }
    if (lane + 64 < d)  { m1 = meta[(size_t)i * SLOTS + lane + 64];  cw[w4][lane + 64]  = m1; }
    if (lane + 128 < d) { m2 = meta[(size_t)i * SLOTS + lane + 128]; cw[w4][lane + 128] = m2; }
    __syncthreads();

    // dedup: slot g is dup iff an earlier slot holds the same col
    int dup0 = 0, dup1 = 0, dup2 = 0;
    for (int s = 0; s < d; ++s) {
        const int cs = cw[w4][s].x;               // uniform addr -> broadcast
        dup0 |= (s < lane)       & (cs == m0.x);
        dup1 |= (s < lane + 64)  & (cs == m1.x);
        dup2 |= (s < lane + 128) & (cs == m2.x);
    }

    float Sp = 0.f;
    if (lane < d)       { if (dup0) cw[w4][lane].y       = 0; else Sp += __int_as_float(m0.y); }
    if (lane + 64 < d)  { if (dup1) cw[w4][lane + 64].y  = 0; else Sp += __int_as_float(m1.y); }
    if (lane + 128 < d) { if (dup2) cw[w4][lane + 128].y = 0; else Sp += __int_as_float(m2.y); }
    const float S = 1.0f + wave_sum(Sp);          // 1.0 = eye diagonal
    __syncthreads();

    float acc = anf[(size_t)i * 64 + lane];       // diagonal: 1.0 * anf[i]
    #pragma unroll 8
    for (int k = 0; k < d; ++k) {
        const int2 ent = cw[w4][k];               // broadcast ds_read_b64
        acc = fmaf(__int_as_float(ent.y), anf[(size_t)ent.x * 64 + lane], acc);
    }

    // ---- projective chain (verified R2-R4) ----
    const float v = acc / (S + EPS);
    const float nv = sqrtf(wave_sum(v * v));
    const float nf = v / (nv + EPS);              // neigh_trans feat

    const float s = s_norm[(size_t)i * 64 + lane];
    const float h = 0.5f * (s + nf);
    const float nh = sqrtf(wave_sum(h * h));
    const float hf = h / (nh + EPS);

    const float bd = bias[lane];
    const float nb = sqrtf(wave_sum(bd * bd) + 1.0f);  // ||[bias,1]||, no eps
    const float g = 0.9f * hf + 0.1f * (bd / nb);
    const float ng = sqrtf(wave_sum(g * g));
    const float gf = g / (ng + EPS);

    const float rho = ng / (ng + EPS);
    out[(size_t)i * 64 + lane] = gf / (rho + EPS);
}

extern "C" void kernel_launch(void* const* d_in, const int* in_sizes, int n_in,
                              void* d_out, int out_size, void* d_ws, size_t ws_size,
                              hipStream_t stream) {
    const float* x      = (const float*)d_in[0];
    const int*   ei     = (const int*)  d_in[1];
    const float* Wself  = (const float*)d_in[2];
    const float* Wneigh = (const float*)d_in[3];
    const float* bias   = (const float*)d_in[4];
    float* out = (float*)d_out;

    // workspace carve-up (~25.1 MB)
    const size_t ROW_BYTES = (size_t)N_NODES * 64 * sizeof(float);
    char* ws = (char*)d_ws;
    int*  deg    = (int*)ws;      ws += (size_t)N_NODES * sizeof(int);
    int2* meta   = (int2*)ws;     ws += (size_t)N_NODES * SLOTS * sizeof(int2);
    float* s_norm = (float*)ws;   ws += ROW_BYTES;
    float* anf    = (float*)ws;   ws += ROW_BYTES;

    hipMemsetAsync(deg, 0, (size_t)N_NODES * sizeof(int), stream);

    edge_scatter_kernel<<<N_EDGES / 8 / 4, 256, 0, stream>>>(x, ei, deg, meta);

    phase1_kernel<<<N_NODES / 4, 256, 0, stream>>>(x, Wself, Wneigh,
                                                   s_norm, anf);

    gather_finalize_kernel<<<N_NODES / 4, 256, 0, stream>>>(deg, meta, anf,
                                                            s_norm, bias, out);
}

// Round 7
// 140.172 us; speedup vs baseline: 2.5391x; 1.1248x over previous
//
#include <hip/hip_runtime.h>
#include <math.h>

#define N_NODES 12288
#define N_EDGES 393216
#define EPS 1e-8f

#define NB 1024            // bins (blocks in pass 2)
#define NPB 12             // nodes per bin: 12288/1024
#define NXCD 8
#define NSUB (NB * NXCD)   // 8192 sub-bins
#define CAP_SUB 256        // records per sub-bin; mean 96, ~16 sigma headroom
#define NSLOT 128          // per-node CSR capacity; unique deg ~Poisson(64), 8 sigma
#define BMW 384            // bitmap words per node: 12288/32

__device__ __forceinline__ float wave_sum(float v) {
    #pragma unroll
    for (int off = 32; off; off >>= 1) v += __shfl_xor(v, off);
    return v;
}

// Phase 1 (unchanged, verified R5): s_norm = (x@Wself^T)/(||.||+eps),
//                                   anf    = (x@Wneigh^T)/(||.||+eps)
__global__ __launch_bounds__(256) void phase1_kernel(
    const float* __restrict__ x, const float* __restrict__ Wself,
    const float* __restrict__ Wneigh,
    float* __restrict__ s_norm, float* __restrict__ anf) {
    __shared__ float Wl[2 * 64 * 65];
    const int tid = threadIdx.x;
    #pragma unroll
    for (int v = 0; v < 4; ++v) {
        const int idx4 = v * 256 + tid;
        const int o = idx4 >> 4, k4 = (idx4 & 15) << 2;
        const float4 a = *(const float4*)&Wself[idx4 << 2];
        Wl[o * 65 + k4 + 0] = a.x; Wl[o * 65 + k4 + 1] = a.y;
        Wl[o * 65 + k4 + 2] = a.z; Wl[o * 65 + k4 + 3] = a.w;
        const float4 b = *(const float4*)&Wneigh[idx4 << 2];
        float* W2 = &Wl[64 * 65];
        W2[o * 65 + k4 + 0] = b.x; W2[o * 65 + k4 + 1] = b.y;
        W2[o * 65 + k4 + 2] = b.z; W2[o * 65 + k4 + 3] = b.w;
    }
    __syncthreads();

    const int o = tid & 63;
    const int i = blockIdx.x * 4 + (tid >> 6);
    const float* xr = &x[(size_t)i * 64];

    float ys = 0.f, yn = 0.f;
    #pragma unroll
    for (int t = 0; t < 16; ++t) {
        const float4 xv = *(const float4*)&xr[4 * t];
        const int kb = 4 * t;
        ys = fmaf(xv.x, Wl[o * 65 + kb + 0], ys);
        ys = fmaf(xv.y, Wl[o * 65 + kb + 1], ys);
        ys = fmaf(xv.z, Wl[o * 65 + kb + 2], ys);
        ys = fmaf(xv.w, Wl[o * 65 + kb + 3], ys);
        yn = fmaf(xv.x, Wl[64 * 65 + o * 65 + kb + 0], yn);
        yn = fmaf(xv.y, Wl[64 * 65 + o * 65 + kb + 1], yn);
        yn = fmaf(xv.z, Wl[64 * 65 + o * 65 + kb + 2], yn);
        yn = fmaf(xv.w, Wl[64 * 65 + o * 65 + kb + 3], yn);
    }

    const float nys = sqrtf(wave_sum(ys * ys));
    const float nyn = sqrtf(wave_sum(yn * yn));
    s_norm[(size_t)i * 64 + o] = ys / (nys + EPS);
    anf[(size_t)i * 64 + o]    = yn / (nyn + EPS);
}

// Pass 1: per edge, compute w inline, emit 2 records (dest<<14|col, wbits) to
// the dest's bin -- replicated PER XCD so each sub-bin's cursor + tail lines
// live in exactly one XCD's L2 (sequential fill -> writeback ~= payload,
// no random-line thrash). Self-edge: .set(w) overwrites (set-1.0 + eye) diag
// -> store w-1 (gather seeds with the eye's 1.0*anf[i]).
// Correctness does NOT depend on the XCC mapping (pass 2 drains all sub-bins);
// xcc is masked to [0,8) so a surprise field value can't escape the bin.
__global__ __launch_bounds__(256) void edge_bin_kernel(
    const float* __restrict__ x, const int* __restrict__ ei,
    int* __restrict__ subcnt, int2* __restrict__ buf) {
    const int lane = threadIdx.x & 63;
    const int j = lane & 7;
    const int wave = blockIdx.x * 4 + (threadIdx.x >> 6);
    const int e = wave * 8 + (lane >> 3);          // N_EDGES = 8*49152 exactly

    const int r = ei[e];
    const int c = ei[N_EDGES + e];

    const size_t rb = (size_t)r * 64 + j * 8;
    const size_t cb = (size_t)c * 64 + j * 8;
    const float4 xr0 = *(const float4*)&x[rb];
    const float4 xr1 = *(const float4*)&x[rb + 4];
    const float4 xc0 = *(const float4*)&x[cb];
    const float4 xc1 = *(const float4*)&x[cb + 4];

    float p = xr0.x*xc0.x + xr0.y*xc0.y + xr0.z*xc0.z + xr0.w*xc0.w
            + xr1.x*xc1.x + xr1.y*xc1.y + xr1.z*xc1.z + xr1.w*xc1.w;
    float nr = xr0.x*xr0.x + xr0.y*xr0.y + xr0.z*xr0.z + xr0.w*xr0.w
             + xr1.x*xr1.x + xr1.y*xr1.y + xr1.z*xr1.z + xr1.w*xr1.w;
    float nc = xc0.x*xc0.x + xc0.y*xc0.y + xc0.z*xc0.z + xc0.w*xc0.w
             + xc1.x*xc1.x + xc1.y*xc1.y + xc1.z*xc1.z + xc1.w*xc1.w;
    #pragma unroll
    for (int off = 1; off < 8; off <<= 1) {
        p  += __shfl_xor(p,  off);
        nr += __shfl_xor(nr, off);
        nc += __shfl_xor(nc, off);
    }

    const float cosv = p / (sqrtf(nr) * sqrtf(nc) + EPS);
    float w = fminf(fmaxf((cosv + 1.0f) * 0.5f, 0.1f), 0.9f);
    const float wv = (r == c) ? (w - 1.0f) : w;
    const int wbits = __float_as_int(wv);

    int xcc;  // HW_REG_XCC_ID = hwreg 20 (gfx940+); returns 0-7 on MI355X (m09)
    asm volatile("s_getreg_b32 %0, hwreg(20, 0, 4)" : "=s"(xcc));
    xcc &= 7;  // safety: mapping is perf-only, but index must stay in-bounds

    if (j < 2) {
        const int dest = j ? c : r;
        const int col  = j ? r : c;
        const int sub = (dest / NPB) * NXCD + xcc;
        const int s = atomicAdd(&subcnt[sub], 1);
        if (s < CAP_SUB)
            buf[(size_t)sub * CAP_SUB + s] = make_int2((dest << 14) | col, wbits);
    }
}

// Pass 2 (fused): block per bin of 12 nodes. Stream the 8 sub-bin segments,
// dedup at INSERT time via LDS bitmap atomicOr (exact .set semantics: all
// copies of (a,b) carry identical w, keep any one), build 12-node CSR in LDS,
// then wave-per-node gather + projective chain. No meta/deg in HBM at all.
__global__ __launch_bounds__(256) void bin_gather_kernel(
    const int* __restrict__ subcnt, const int2* __restrict__ buf,
    const float* __restrict__ anf, const float* __restrict__ s_norm,
    const float* __restrict__ bias, float* __restrict__ out) {
    __shared__ int2 csr[NPB][NSLOT];        // 12 KB
    __shared__ unsigned bm[NPB * BMW];      // 18 KB
    __shared__ int cnt[NPB];
    const int tid = threadIdx.x;
    const int lane = tid & 63;
    const int w4 = tid >> 6;
    const int bin = blockIdx.x;
    const int node0 = bin * NPB;

    for (int t = tid; t < NPB * BMW; t += 256) bm[t] = 0u;
    if (tid < NPB) cnt[tid] = 0;
    __syncthreads();

    for (int xc = 0; xc < NXCD; ++xc) {
        const int sub = bin * NXCD + xc;
        const int n = min(subcnt[sub], CAP_SUB);
        const int2* seg = &buf[(size_t)sub * CAP_SUB];
        for (int t = tid; t < n; t += 256) {
            const int2 rec = seg[t];
            const int dest = rec.x >> 14;
            const int col  = rec.x & 16383;
            const int l = dest - node0;
            const unsigned bit = 1u << (col & 31);
            const unsigned old = atomicOr(&bm[l * BMW + (col >> 5)], bit);
            if (!(old & bit)) {
                const int s = atomicAdd(&cnt[l], 1);
                if (s < NSLOT) csr[l][s] = make_int2(col, rec.y);
            }
        }
    }
    __syncthreads();

    // bias term: wave-invariant, hoisted out of the node loop
    const float bd = bias[lane];
    const float nb = sqrtf(wave_sum(bd * bd) + 1.0f);   // ||[bias,1]||, no eps
    const float bterm = 0.1f * (bd / nb);

    #pragma unroll 1
    for (int q = 0; q < 3; ++q) {
        const int l = w4 * 3 + q;
        const int i = node0 + l;
        const int d = min(cnt[l], NSLOT);

        float acc = anf[(size_t)i * 64 + lane];   // eye diagonal: 1.0*anf[i]
        #pragma unroll 4
        for (int k = 0; k < d; ++k) {
            const int2 ent = csr[l][k];           // wave-uniform broadcast
            acc = fmaf(__int_as_float(ent.y), anf[(size_t)ent.x * 64 + lane], acc);
        }
        float Sp = 0.f;
        if (lane < d)      Sp += __int_as_float(csr[l][lane].y);
        if (lane + 64 < d) Sp += __int_as_float(csr[l][lane + 64].y);
        const float S = 1.0f + wave_sum(Sp);

        // ---- projective chain (verified R2-R5) ----
        const float v = acc / (S + EPS);
        const float nv = sqrtf(wave_sum(v * v));
        const float nf = v / (nv + EPS);          // neigh_trans feat

        const float s = s_norm[(size_t)i * 64 + lane];
        const float h = 0.5f * (s + nf);
        const float nh = sqrtf(wave_sum(h * h));
        const float hf = h / (nh + EPS);

        const float g = 0.9f * hf + bterm;
        const float ng = sqrtf(wave_sum(g * g));
        const float gf = g / (ng + EPS);

        const float rho = ng / (ng + EPS);
        out[(size_t)i * 64 + lane] = gf / (rho + EPS);
    }
}

extern "C" void kernel_launch(void* const* d_in, const int* in_sizes, int n_in,
                              void* d_out, int out_size, void* d_ws, size_t ws_size,
                              hipStream_t stream) {
    const float* x      = (const float*)d_in[0];
    const int*   ei     = (const int*)  d_in[1];
    const float* Wself  = (const float*)d_in[2];
    const float* Wneigh = (const float*)d_in[3];
    const float* bias   = (const float*)d_in[4];
    float* out = (float*)d_out;

    // workspace carve-up (~22.9 MB)
    const size_t ROW_BYTES = (size_t)N_NODES * 64 * sizeof(float);
    char* ws = (char*)d_ws;
    int*  subcnt = (int*)ws;   ws += (size_t)NSUB * sizeof(int);            // 32 KB
    int2* buf    = (int2*)ws;  ws += (size_t)NSUB * CAP_SUB * sizeof(int2); // 16.8 MB
    float* s_norm = (float*)ws; ws += ROW_BYTES;                            // 3 MB
    float* anf    = (float*)ws; ws += ROW_BYTES;                            // 3 MB

    hipMemsetAsync(subcnt, 0, (size_t)NSUB * sizeof(int), stream);

    edge_bin_kernel<<<N_EDGES / 8 / 4, 256, 0, stream>>>(x, ei, subcnt, buf);

    phase1_kernel<<<N_NODES / 4, 256, 0, stream>>>(x, Wself, Wneigh,
                                                   s_norm, anf);

    bin_gather_kernel<<<NB, 256, 0, stream>>>(subcnt, buf, anf, s_norm,
                                              bias, out);
}

// Round 8
// 136.778 us; speedup vs baseline: 2.6020x; 1.0248x over previous
//
#include <hip/hip_runtime.h>
#include <math.h>

#define N_NODES 12288
#define N_EDGES 393216
#define EPS 1e-8f

#define NB 1024            // bins (blocks in pass 2)
#define NPB 12             // nodes per bin: 12288/1024
#define NXCD 8
#define NSUB (NB * NXCD)   // 8192 sub-bins
#define CAP_SUB 256        // records per sub-bin; mean 96, ~16 sigma headroom
#define NSLOT 128          // per-node CSR capacity; unique deg ~Poisson(64), 8 sigma
#define BMW 384            // bitmap words per node: 12288/32

__device__ __forceinline__ float wave_sum(float v) {
    #pragma unroll
    for (int off = 32; off; off >>= 1) v += __shfl_xor(v, off);
    return v;
}

// Phase 1 v3: grid 768, 4 waves/block, 4 NODES PER WAVE.
//  - W staged once per block (24 MB total L2->LDS vs 98 MB at grid 3072)
//  - each LDS W element feeds 8 FMAs (4 nodes x 2 matrices) -> DS instrs/node
//    cut 4x vs v2. Per-node FMA order identical to v2 (absmax-stable).
// Wl pad 65: lane o reads row o, bank (o+k)%32 -> 2-way alias only (free, m136);
// adjacent k pairs merge to ds_read2_b32 off one base vaddr + imm offsets.
__global__ __launch_bounds__(256) void phase1_kernel(
    const float* __restrict__ x, const float* __restrict__ Wself,
    const float* __restrict__ Wneigh,
    float* __restrict__ s_norm, float* __restrict__ anf) {
    __shared__ float Wl[2 * 64 * 65];
    const int tid = threadIdx.x;
    #pragma unroll
    for (int v = 0; v < 4; ++v) {
        const int idx4 = v * 256 + tid;
        const int o = idx4 >> 4, k4 = (idx4 & 15) << 2;
        const float4 a = *(const float4*)&Wself[idx4 << 2];
        Wl[o * 65 + k4 + 0] = a.x; Wl[o * 65 + k4 + 1] = a.y;
        Wl[o * 65 + k4 + 2] = a.z; Wl[o * 65 + k4 + 3] = a.w;
        const float4 b = *(const float4*)&Wneigh[idx4 << 2];
        float* W2 = &Wl[64 * 65];
        W2[o * 65 + k4 + 0] = b.x; W2[o * 65 + k4 + 1] = b.y;
        W2[o * 65 + k4 + 2] = b.z; W2[o * 65 + k4 + 3] = b.w;
    }
    __syncthreads();

    const int o = tid & 63;
    const int wq = tid >> 6;
    const int i0 = (blockIdx.x * 4 + wq) * 4;     // grid 768: 768*4*4 = 12288
    const float* xr0 = &x[(size_t)(i0 + 0) * 64];
    const float* xr1 = &x[(size_t)(i0 + 1) * 64];
    const float* xr2 = &x[(size_t)(i0 + 2) * 64];
    const float* xr3 = &x[(size_t)(i0 + 3) * 64];
    const float* Ws = &Wl[o * 65];
    const float* Wn = &Wl[64 * 65 + o * 65];

    float ys0 = 0.f, ys1 = 0.f, ys2 = 0.f, ys3 = 0.f;
    float yn0 = 0.f, yn1 = 0.f, yn2 = 0.f, yn3 = 0.f;
    #pragma unroll
    for (int t = 0; t < 16; ++t) {
        const int kb = 4 * t;
        const float4 a0 = *(const float4*)&xr0[kb];   // wave-uniform addr
        const float4 a1 = *(const float4*)&xr1[kb];
        const float4 a2 = *(const float4*)&xr2[kb];
        const float4 a3 = *(const float4*)&xr3[kb];
        #pragma unroll
        for (int u = 0; u < 4; ++u) {
            const float ws = Ws[kb + u];
            const float wn = Wn[kb + u];
            const float e0 = u == 0 ? a0.x : u == 1 ? a0.y : u == 2 ? a0.z : a0.w;
            const float e1 = u == 0 ? a1.x : u == 1 ? a1.y : u == 2 ? a1.z : a1.w;
            const float e2 = u == 0 ? a2.x : u == 1 ? a2.y : u == 2 ? a2.z : a2.w;
            const float e3 = u == 0 ? a3.x : u == 1 ? a3.y : u == 2 ? a3.z : a3.w;
            ys0 = fmaf(e0, ws, ys0); yn0 = fmaf(e0, wn, yn0);
            ys1 = fmaf(e1, ws, ys1); yn1 = fmaf(e1, wn, yn1);
            ys2 = fmaf(e2, ws, ys2); yn2 = fmaf(e2, wn, yn2);
            ys3 = fmaf(e3, ws, ys3); yn3 = fmaf(e3, wn, yn3);
        }
    }

    const float ns0 = sqrtf(wave_sum(ys0 * ys0));
    const float ns1 = sqrtf(wave_sum(ys1 * ys1));
    const float ns2 = sqrtf(wave_sum(ys2 * ys2));
    const float ns3 = sqrtf(wave_sum(ys3 * ys3));
    const float nn0 = sqrtf(wave_sum(yn0 * yn0));
    const float nn1 = sqrtf(wave_sum(yn1 * yn1));
    const float nn2 = sqrtf(wave_sum(yn2 * yn2));
    const float nn3 = sqrtf(wave_sum(yn3 * yn3));

    s_norm[(size_t)(i0 + 0) * 64 + o] = ys0 / (ns0 + EPS);
    s_norm[(size_t)(i0 + 1) * 64 + o] = ys1 / (ns1 + EPS);
    s_norm[(size_t)(i0 + 2) * 64 + o] = ys2 / (ns2 + EPS);
    s_norm[(size_t)(i0 + 3) * 64 + o] = ys3 / (ns3 + EPS);
    anf[(size_t)(i0 + 0) * 64 + o] = yn0 / (nn0 + EPS);
    anf[(size_t)(i0 + 1) * 64 + o] = yn1 / (nn1 + EPS);
    anf[(size_t)(i0 + 2) * 64 + o] = yn2 / (nn2 + EPS);
    anf[(size_t)(i0 + 3) * 64 + o] = yn3 / (nn3 + EPS);
}

// Pass 1 (unchanged from R7): per edge, compute w inline, emit 2 records
// (dest<<14|col, wbits) to the dest's bin -- replicated PER XCD so sub-bin
// cursor+tail lines live in one XCD's L2. Self-edge: store w-1 (gather seeds
// with the eye's 1.0*anf[i]; .set semantics handled by gather-side dedup).
__global__ __launch_bounds__(256) void edge_bin_kernel(
    const float* __restrict__ x, const int* __restrict__ ei,
    int* __restrict__ subcnt, int2* __restrict__ buf) {
    const int lane = threadIdx.x & 63;
    const int j = lane & 7;
    const int wave = blockIdx.x * 4 + (threadIdx.x >> 6);
    const int e = wave * 8 + (lane >> 3);          // N_EDGES = 8*49152 exactly

    const int r = ei[e];
    const int c = ei[N_EDGES + e];

    const size_t rb = (size_t)r * 64 + j * 8;
    const size_t cb = (size_t)c * 64 + j * 8;
    const float4 xr0 = *(const float4*)&x[rb];
    const float4 xr1 = *(const float4*)&x[rb + 4];
    const float4 xc0 = *(const float4*)&x[cb];
    const float4 xc1 = *(const float4*)&x[cb + 4];

    float p = xr0.x*xc0.x + xr0.y*xc0.y + xr0.z*xc0.z + xr0.w*xc0.w
            + xr1.x*xc1.x + xr1.y*xc1.y + xr1.z*xc1.z + xr1.w*xc1.w;
    float nr = xr0.x*xr0.x + xr0.y*xr0.y + xr0.z*xr0.z + xr0.w*xr0.w
             + xr1.x*xr1.x + xr1.y*xr1.y + xr1.z*xr1.z + xr1.w*xr1.w;
    float nc = xc0.x*xc0.x + xc0.y*xc0.y + xc0.z*xc0.z + xc0.w*xc0.w
             + xc1.x*xc1.x + xc1.y*xc1.y + xc1.z*xc1.z + xc1.w*xc1.w;
    #pragma unroll
    for (int off = 1; off < 8; off <<= 1) {
        p  += __shfl_xor(p,  off);
        nr += __shfl_xor(nr, off);
        nc += __shfl_xor(nc, off);
    }

    const float cosv = p / (sqrtf(nr) * sqrtf(nc) + EPS);
    float w = fminf(fmaxf((cosv + 1.0f) * 0.5f, 0.1f), 0.9f);
    const float wv = (r == c) ? (w - 1.0f) : w;
    const int wbits = __float_as_int(wv);

    int xcc;  // HW_REG_XCC_ID = hwreg 20 (gfx940+); returns 0-7 on MI355X (m09)
    asm volatile("s_getreg_b32 %0, hwreg(20, 0, 4)" : "=s"(xcc));
    xcc &= 7;  // mapping is perf-only, but index must stay in-bounds

    if (j < 2) {
        const int dest = j ? c : r;
        const int col  = j ? r : c;
        const int sub = (dest / NPB) * NXCD + xcc;
        const int s = atomicAdd(&subcnt[sub], 1);
        if (s < CAP_SUB)
            buf[(size_t)sub * CAP_SUB + s] = make_int2((dest << 14) | col, wbits);
    }
}

// Pass 2 (unchanged from R7): block per bin of 12 nodes; stream sub-bin
// segments, insert-time LDS-bitmap dedup (.set semantics), LDS CSR, then
// wave-per-node gather + projective chain.
__global__ __launch_bounds__(256) void bin_gather_kernel(
    const int* __restrict__ subcnt, const int2* __restrict__ buf,
    const float* __restrict__ anf, const float* __restrict__ s_norm,
    const float* __restrict__ bias, float* __restrict__ out) {
    __shared__ int2 csr[NPB][NSLOT];        // 12 KB
    __shared__ unsigned bm[NPB * BMW];      // 18 KB
    __shared__ int cnt[NPB];
    const int tid = threadIdx.x;
    const int lane = tid & 63;
    const int w4 = tid >> 6;
    const int bin = blockIdx.x;
    const int node0 = bin * NPB;

    for (int t = tid; t < NPB * BMW; t += 256) bm[t] = 0u;
    if (tid < NPB) cnt[tid] = 0;
    __syncthreads();

    for (int xc = 0; xc < NXCD; ++xc) {
        const int sub = bin * NXCD + xc;
        const int n = min(subcnt[sub], CAP_SUB);
        const int2* seg = &buf[(size_t)sub * CAP_SUB];
        for (int t = tid; t < n; t += 256) {
            const int2 rec = seg[t];
            const int dest = rec.x >> 14;
            const int col  = rec.x & 16383;
            const int l = dest - node0;
            const unsigned bit = 1u << (col & 31);
            const unsigned old = atomicOr(&bm[l * BMW + (col >> 5)], bit);
            if (!(old & bit)) {
                const int s = atomicAdd(&cnt[l], 1);
                if (s < NSLOT) csr[l][s] = make_int2(col, rec.y);
            }
        }
    }
    __syncthreads();

    // bias term: wave-invariant, hoisted out of the node loop
    const float bd = bias[lane];
    const float nb = sqrtf(wave_sum(bd * bd) + 1.0f);   // ||[bias,1]||, no eps
    const float bterm = 0.1f * (bd / nb);

    #pragma unroll 1
    for (int q = 0; q < 3; ++q) {
        const int l = w4 * 3 + q;
        const int i = node0 + l;
        const int d = min(cnt[l], NSLOT);

        float acc = anf[(size_t)i * 64 + lane];   // eye diagonal: 1.0*anf[i]
        #pragma unroll 4
        for (int k = 0; k < d; ++k) {
            const int2 ent = csr[l][k];           // wave-uniform broadcast
            acc = fmaf(__int_as_float(ent.y), anf[(size_t)ent.x * 64 + lane], acc);
        }
        float Sp = 0.f;
        if (lane < d)      Sp += __int_as_float(csr[l][lane].y);
        if (lane + 64 < d) Sp += __int_as_float(csr[l][lane + 64].y);
        const float S = 1.0f + wave_sum(Sp);

        // ---- projective chain (verified R2-R7) ----
        const float v = acc / (S + EPS);
        const float nv = sqrtf(wave_sum(v * v));
        const float nf = v / (nv + EPS);          // neigh_trans feat

        const float s = s_norm[(size_t)i * 64 + lane];
        const float h = 0.5f * (s + nf);
        const float nh = sqrtf(wave_sum(h * h));
        const float hf = h / (nh + EPS);

        const float g = 0.9f * hf + bterm;
        const float ng = sqrtf(wave_sum(g * g));
        const float gf = g / (ng + EPS);

        const float rho = ng / (ng + EPS);
        out[(size_t)i * 64 + lane] = gf / (rho + EPS);
    }
}

extern "C" void kernel_launch(void* const* d_in, const int* in_sizes, int n_in,
                              void* d_out, int out_size, void* d_ws, size_t ws_size,
                              hipStream_t stream) {
    const float* x      = (const float*)d_in[0];
    const int*   ei     = (const int*)  d_in[1];
    const float* Wself  = (const float*)d_in[2];
    const float* Wneigh = (const float*)d_in[3];
    const float* bias   = (const float*)d_in[4];
    float* out = (float*)d_out;

    // workspace carve-up (~22.9 MB)
    const size_t ROW_BYTES = (size_t)N_NODES * 64 * sizeof(float);
    char* ws = (char*)d_ws;
    int*  subcnt = (int*)ws;   ws += (size_t)NSUB * sizeof(int);            // 32 KB
    int2* buf    = (int2*)ws;  ws += (size_t)NSUB * CAP_SUB * sizeof(int2); // 16.8 MB
    float* s_norm = (float*)ws; ws += ROW_BYTES;                            // 3 MB
    float* anf    = (float*)ws; ws += ROW_BYTES;                            // 3 MB

    hipMemsetAsync(subcnt, 0, (size_t)NSUB * sizeof(int), stream);

    edge_bin_kernel<<<N_EDGES / 8 / 4, 256, 0, stream>>>(x, ei, subcnt, buf);

    phase1_kernel<<<768, 256, 0, stream>>>(x, Wself, Wneigh, s_norm, anf);

    bin_gather_kernel<<<NB, 256, 0, stream>>>(subcnt, buf, anf, s_norm,
                                              bias, out);
}